// Round 9
// baseline (34.533 us; speedup 1.0000x reference)
//
#include <hip/hip_runtime.h>
#include <math.h>

// Split fill-mimic.
// A: csw[i][bh] = (c,s)/W  — per-row 128-pt DFT at freq i, i-major layout (2 MiB in d_ws)
// B: block = output plane (b,i) = blockIdx -> consecutive blocks write consecutive
//    64 KB planes (fill-identical walk). Stage 1 KB of (c,s) coalesced, then
//    16 x {2 LDS broadcasts + 8 FMA + 1 KB-contiguous wave store}.

#define WDIM 128
#define BLK 256
#define PI_OVER_64 0.04908738521234052f   // 2*pi/128

typedef float vfloat4 __attribute__((ext_vector_type(4)));

__global__ __launch_bounds__(BLK) void kspace_cs_kernel(
    const float* __restrict__ in, float2* __restrict__ csw) {
    const int bh = blockIdx.x;             // 0..2047
    __shared__ float x[WDIM];
    __shared__ float cp[BLK];
    __shared__ float sp[BLK];

    const int t = threadIdx.x;
    if (t < WDIM) x[t] = in[(size_t)bh * WDIM + t];

    const int i    = t & 127;
    const int half = t >> 7;               // 0/1
    const int base = half << 6;            // 0/64

    const float a0 = (float)((i * base) & 127) * PI_OVER_64;
    float C = __cosf(a0);
    float S = __sinf(a0);
    const float as = (float)i * PI_OVER_64;
    const float stC = __cosf(as);
    const float stS = __sinf(as);
    __syncthreads();

    float cc = 0.0f, ss = 0.0f;
    #pragma unroll
    for (int k = 0; k < 64; ++k) {
        const float xv = x[base + k];      // wave-uniform broadcast
        cc = fmaf(xv, C, cc);
        ss = fmaf(xv, S, ss);
        const float nC = fmaf(C, stC, -(S * stS));
        const float nS = fmaf(S, stC,  (C * stS));
        C = nC; S = nS;
    }
    cp[t] = cc; sp[t] = ss;
    __syncthreads();
    if (t < WDIM) {
        const float invW = 1.0f / (float)WDIM;
        float2 v;
        v.x = (cp[t] + cp[t + 128]) * invW;
        v.y = (sp[t] + sp[t + 128]) * invW;
        csw[(size_t)t * 2048 + bh] = v;    // i-major (scattered 8B; 2 MiB total)
    }
}

__global__ __launch_bounds__(BLK) void kspace_write_kernel(
    const float2* __restrict__ csw, float* __restrict__ out) {
    const int blk = blockIdx.x;            // = output plane index b*128+i
    const int i = blk & 127;
    const int b = blk >> 7;

    __shared__ float2 csl[WDIM];

    const int t = threadIdx.x;
    if (t < WDIM)                          // coalesced 1 KB stage (L2/L3-hot)
        csl[t] = csw[(size_t)i * 2048 + (b << 7) + t];

    const int col = t & 31;
    const int r   = t >> 5;                // 0..7
    const int w0  = col << 2;

    // basis at (i, w0..w0+3), computed once per thread
    const float as = (float)i * PI_OVER_64;
    const float stC = __cosf(as);
    const float stS = __sinf(as);
    const float a0 = (float)((i * w0) & 127) * PI_OVER_64;
    const float Cv0 = __cosf(a0);
    const float Sv0 = __sinf(a0);
    const float Cv1 = fmaf(Cv0, stC, -(Sv0 * stS));
    const float Sv1 = fmaf(Sv0, stC,  (Cv0 * stS));
    const float Cv2 = fmaf(Cv1, stC, -(Sv1 * stS));
    const float Sv2 = fmaf(Sv1, stC,  (Cv1 * stS));
    const float Cv3 = fmaf(Cv2, stC, -(Sv2 * stS));
    const float Sv3 = fmaf(Sv2, stC,  (Cv2 * stS));

    __syncthreads();

    float* op = out + ((size_t)blk << 14); // contiguous 64 KB plane
    #pragma unroll
    for (int ii = 0; ii < 16; ++ii) {
        const int hp = (ii << 3) + r;      // 0..127; wave = rows hp,hp+1 -> 1 KB
        const float2 v2 = csl[hp];         // broadcast (2 addrs/wave)
        const float ci = v2.x;
        const float si = v2.y;
        vfloat4 v;
        v.x = fmaf(ci, Cv0, si * Sv0);
        v.y = fmaf(ci, Cv1, si * Sv1);
        v.z = fmaf(ci, Cv2, si * Sv2);
        v.w = fmaf(ci, Cv3, si * Sv3);
        *reinterpret_cast<vfloat4*>(op + (hp << 7) + w0) = v;
    }
}

extern "C" void kernel_launch(void* const* d_in, const int* in_sizes, int n_in,
                              void* d_out, int out_size, void* d_ws, size_t ws_size,
                              hipStream_t stream) {
    const float* in = (const float*)d_in[0];   // (16,1,128,128) fp32
    float* out = (float*)d_out;                // (16,128,128,128) fp32
    float2* csw = (float2*)d_ws;               // 2 MiB scratch

    hipLaunchKernelGGL(kspace_cs_kernel, dim3(2048), dim3(BLK), 0, stream, in, csw);
    hipLaunchKernelGGL(kspace_write_kernel, dim3(16 * 128), dim3(BLK), 0, stream, csw, out);
}

// Round 10
// 28.830 us; speedup vs baseline: 1.1978x; 1.1978x over previous
//
#include <hip/hip_runtime.h>
#include <math.h>

// Single-kernel fill-mimic: block = output plane (b,i) (2048 blocks x 1024 thr).
// Phase 1: c,s for 128 rows of batch b at freq i (8 thr/row, 16-term rotation
// chains, shfl-reduce, 1 barrier). Input rows come from L2 (1 MiB resident;
// dup reads ~128 MiB aggregate @ L2 rate, hidden by 2-deep block pipelining).
// Phase 2: 4 x {2 LDS broadcasts + 8 FMA + 16 KB block-contiguous store};
// consecutive blocks write consecutive 64 KB planes -> fill-identical walk.

#define WDIM 128
#define PI_OVER_64 0.04908738521234052f   // 2*pi/128

typedef float vfloat4 __attribute__((ext_vector_type(4)));

__global__ __launch_bounds__(1024) void kspace_map_kernel(
    const float* __restrict__ in, float* __restrict__ out) {
    const int blk = blockIdx.x;        // plane index b*128 + i
    const int i = blk & 127;
    const int b = blk >> 7;

    __shared__ float cS[WDIM];
    __shared__ float sS[WDIM];

    const int t = threadIdx.x;

    // ---- phase 1: row = t>>3 (0..127), seg = t&7, 16-term chain ----
    const int row = t >> 3;
    const int seg = t & 7;
    const int k0  = seg << 4;

    // issue input loads first (L2-resident after first few blocks)
    const float* xr = in + ((size_t)b << 14) + (row << 7) + k0;
    vfloat4 x0 = *(const vfloat4*)(xr + 0);
    vfloat4 x1 = *(const vfloat4*)(xr + 4);
    vfloat4 x2 = *(const vfloat4*)(xr + 8);
    vfloat4 x3 = *(const vfloat4*)(xr + 12);

    const float as  = (float)i * PI_OVER_64;
    const float stC = __cosf(as);
    const float stS = __sinf(as);

    {
        float C = __cosf((float)((i * k0) & 127) * PI_OVER_64);
        float S = __sinf((float)((i * k0) & 127) * PI_OVER_64);

        float xs[16];
        *reinterpret_cast<vfloat4*>(&xs[0])  = x0;
        *reinterpret_cast<vfloat4*>(&xs[4])  = x1;
        *reinterpret_cast<vfloat4*>(&xs[8])  = x2;
        *reinterpret_cast<vfloat4*>(&xs[12]) = x3;
        float cc = 0.0f, ss = 0.0f;
        #pragma unroll
        for (int k = 0; k < 16; ++k) {
            const float xv = xs[k];
            cc = fmaf(xv, C, cc);
            ss = fmaf(xv, S, ss);
            const float nC = fmaf(C, stC, -(S * stS));
            const float nS = fmaf(S, stC,  (C * stS));
            C = nC; S = nS;
        }
        cc += __shfl_xor(cc, 1); ss += __shfl_xor(ss, 1);
        cc += __shfl_xor(cc, 2); ss += __shfl_xor(ss, 2);
        cc += __shfl_xor(cc, 4); ss += __shfl_xor(ss, 4);
        if (seg == 0) {
            const float invW = 1.0f / (float)WDIM;
            cS[row] = cc * invW;
            sS[row] = ss * invW;
        }
    }

    // ---- phase-2 per-thread basis (before barrier to overlap) ----
    const int lane = t & 63;
    const int wv   = t >> 6;           // 0..15
    const int col  = lane & 31;
    const int hpar = lane >> 5;        // 0/1
    const int w0   = col << 2;

    const float a0 = (float)((i * w0) & 127) * PI_OVER_64;
    const float Cv0 = __cosf(a0);
    const float Sv0 = __sinf(a0);
    const float Cv1 = fmaf(Cv0, stC, -(Sv0 * stS));
    const float Sv1 = fmaf(Sv0, stC,  (Cv0 * stS));
    const float Cv2 = fmaf(Cv1, stC, -(Sv1 * stS));
    const float Sv2 = fmaf(Sv1, stC,  (Cv1 * stS));
    const float Cv3 = fmaf(Cv2, stC, -(Sv2 * stS));
    const float Sv3 = fmaf(Sv2, stC,  (Cv2 * stS));

    __syncthreads();

    // ---- phase 2: 4 x 16 KB block-contiguous stores, sequential walk ----
    float* op = out + ((size_t)blk << 14);
    #pragma unroll
    for (int ii = 0; ii < 4; ++ii) {
        const int hp = (wv << 1) + hpar + (ii << 5);   // 0..127, all distinct
        const float ci = cS[hp];       // 2-addr broadcast per wave (free)
        const float si = sS[hp];
        vfloat4 v;
        v.x = fmaf(ci, Cv0, si * Sv0);
        v.y = fmaf(ci, Cv1, si * Sv1);
        v.z = fmaf(ci, Cv2, si * Sv2);
        v.w = fmaf(ci, Cv3, si * Sv3);
        *reinterpret_cast<vfloat4*>(op + (hp << 7) + w0) = v;
    }
}

extern "C" void kernel_launch(void* const* d_in, const int* in_sizes, int n_in,
                              void* d_out, int out_size, void* d_ws, size_t ws_size,
                              hipStream_t stream) {
    const float* in = (const float*)d_in[0];   // (16,1,128,128) fp32
    float* out = (float*)d_out;                // (16,128,128,128) fp32
    dim3 grid(16 * 128);                       // one block per output plane
    dim3 block(1024);
    hipLaunchKernelGGL(kspace_map_kernel, grid, block, 0, stream, in, out);
}

// Round 11
// 27.057 us; speedup vs baseline: 1.2763x; 1.0655x over previous
//
#include <hip/hip_runtime.h>
#include <math.h>

// out[b, i, h, w] = (1/W) * ( cos(2pi*i*w/W)*c[b,h,i] + sin(2pi*i*w/W)*s[b,h,i] )
// c[i] = sum_w' x[w'] cos(2pi*i*w'/W), s[i] = sum_w' x[w'] sin(2pi*i*w'/W)
// (the H-axis IFFT cancels exactly; everything is per input row)
//
// Best-measured structure (R3, 26.9 us): block = (row bh, i-quarter q).
// Each block computes c,s for its 32 i-values only (exact partition of
// phase-1 work) and stores a 32x128 slice as 512B-coalesced float4 stores.
// 4 residency batches pipeline so later heads hide under earlier stores.
// All trig via native v_sin/v_cos on &127-reduced angles + rotation chains.

#define WDIM 128
#define BLK 256
#define PI_OVER_64 0.04908738521234052f   // pi/64 = 2*pi/128

__global__ __launch_bounds__(BLK) void kspace_map_kernel(
    const float* __restrict__ in, float* __restrict__ out) {
    const int blk = blockIdx.x;            // 0 .. 8191
    const int bh  = blk >> 2;              // row 0..2047
    const int q   = blk & 3;               // i-quarter 0..3
    const int b   = bh >> 7;
    const int h   = bh & 127;

    __shared__ float x[WDIM];
    __shared__ float cpart[BLK];
    __shared__ float spart[BLK];
    __shared__ float cS[32];
    __shared__ float sS[32];

    const int t = threadIdx.x;

    if (t < WDIM) x[t] = in[(size_t)bh * WDIM + t];

    // ---- phase-1 setup: thread = (seg, i_local); 8 segs x 16 terms ----
    const int il  = t & 31;                // i_local 0..31
    const int seg = t >> 5;                // 0..7
    const int ig1 = (q << 5) + il;         // global i for phase 1
    const int k0  = seg << 4;              // start k = 16*seg

    float C, S, stC, stS;
    {
        const int idx0 = (ig1 * k0) & 127;
        const float a0 = (float)idx0 * PI_OVER_64;
        C = __cosf(a0);
        S = __sinf(a0);
        const float as = (float)ig1 * PI_OVER_64;   // ig1 < 128, in range
        stC = __cosf(as);
        stS = __sinf(as);
    }
    __syncthreads();

    // ---- phase 1: 16-term partial DFT via rotation chain ----
    {
        float cc = 0.0f, sc = 0.0f;
        #pragma unroll
        for (int k = 0; k < 16; ++k) {
            const float xv = x[k0 + k];    // wave-uniform broadcast
            cc = fmaf(xv, C, cc);
            sc = fmaf(xv, S, sc);
            const float nC = fmaf(C, stC, -(S * stS));
            const float nS = fmaf(S, stC,  (C * stS));
            C = nC; S = nS;
        }
        cpart[t] = cc;
        spart[t] = sc;
    }
    __syncthreads();

    // ---- reduce 8 partials per i (conflict-free: lane j hits bank j) ----
    if (t < 64) {
        const int j = t & 31;
        if (t < 32) {
            float a = 0.f;
            #pragma unroll
            for (int g = 0; g < 8; ++g) a += cpart[j + (g << 5)];
            cS[j] = a;
        } else {
            float a = 0.f;
            #pragma unroll
            for (int g = 0; g < 8; ++g) a += spart[j + (g << 5)];
            sS[j] = a;
        }
    }
    __syncthreads();

    // ---- phase 2: store 32x128 slice, 4 float4 per thread ----
    const float invW = 1.0f / (float)WDIM;
    const int col   = t & 31;
    const int r     = t >> 5;              // 0..7
    const int wbase = col << 2;            // 0,4,...,124
    // out offset: b*2^21 + i*2^14 + h*2^7 + w
    float* outp = out + ((size_t)b << 21) + ((size_t)h << 7);

    #pragma unroll
    for (int ii = 0; ii < 4; ++ii) {
        const int ir = r + (ii << 3);      // local i 0..31
        const int ig = (q << 5) + ir;      // global i
        const float ci = cS[ir] * invW;    // 2-address broadcast per wave
        const float si = sS[ir] * invW;

        const int idx0 = (ig * wbase) & 127;
        const float a0 = (float)idx0 * PI_OVER_64;
        float Cv = __cosf(a0);
        float Sv = __sinf(a0);
        const float as = (float)ig * PI_OVER_64;
        const float rC = __cosf(as);
        const float rS = __sinf(as);

        float4 v;
        v.x = fmaf(ci, Cv, si * Sv);
        float C1 = fmaf(Cv, rC, -(Sv * rS));
        float S1 = fmaf(Sv, rC,  (Cv * rS));
        v.y = fmaf(ci, C1, si * S1);
        float C2 = fmaf(C1, rC, -(S1 * rS));
        float S2 = fmaf(S1, rC,  (C1 * rS));
        v.z = fmaf(ci, C2, si * S2);
        float C3 = fmaf(C2, rC, -(S2 * rS));
        float S3 = fmaf(S2, rC,  (C2 * rS));
        v.w = fmaf(ci, C3, si * S3);

        *reinterpret_cast<float4*>(outp + ((size_t)ig << 14) + wbase) = v;
    }
}

extern "C" void kernel_launch(void* const* d_in, const int* in_sizes, int n_in,
                              void* d_out, int out_size, void* d_ws, size_t ws_size,
                              hipStream_t stream) {
    const float* in = (const float*)d_in[0];   // (16,1,128,128) fp32
    float* out = (float*)d_out;                // (16,128,128,128) fp32
    const int B = 16, H = 128;
    dim3 grid(B * H * 4);
    dim3 block(BLK);
    hipLaunchKernelGGL(kspace_map_kernel, grid, block, 0, stream, in, out);
}